// Round 1
// baseline (232.204 us; speedup 1.0000x reference)
//
#include <hip/hip_runtime.h>

typedef __fp16 fp16x2 __attribute__((ext_vector_type(2)));   // cvt_pkrtz result type
typedef _Float16 half8 __attribute__((ext_vector_type(8)));
typedef float floatx4 __attribute__((ext_vector_type(4)));

namespace {

constexpr int NODES = 512;   // nodes per graph
constexpr int DIM   = 256;   // latent dim
constexpr int BM    = 128;   // block tile (rows and cols)
constexpr int BK    = 64;    // K-step per LDS stage (fp16): row = 128 B = 8 x 16B chunks

union Cvt8 { fp16x2 h2[4]; half8 h8; };

__device__ inline half8 pack8(const floatx4 f0, const floatx4 f1) {
  Cvt8 c;
  c.h2[0] = __builtin_amdgcn_cvt_pkrtz(f0.x, f0.y);
  c.h2[1] = __builtin_amdgcn_cvt_pkrtz(f0.z, f0.w);
  c.h2[2] = __builtin_amdgcn_cvt_pkrtz(f1.x, f1.y);
  c.h2[3] = __builtin_amdgcn_cvt_pkrtz(f1.z, f1.w);
  return c.h8;
}

__device__ inline half8 pack8(const float4 f0, const float4 f1) {
  Cvt8 c;
  c.h2[0] = __builtin_amdgcn_cvt_pkrtz(f0.x, f0.y);
  c.h2[1] = __builtin_amdgcn_cvt_pkrtz(f0.z, f0.w);
  c.h2[2] = __builtin_amdgcn_cvt_pkrtz(f1.x, f1.y);
  c.h2[3] = __builtin_amdgcn_cvt_pkrtz(f1.z, f1.w);
  return c.h8;
}

// async 16-B global -> LDS DMA; LDS dest = wave-uniform base + lane*16
__device__ inline void async_ld16(const void* g, void* lds) {
  __builtin_amdgcn_global_load_lds(
      (const __attribute__((address_space(1))) unsigned int*)g,
      (__attribute__((address_space(3))) unsigned int*)lds,
      16, 0, 0);
}

// ---------- kernel 1: fp32 -> fp16 pre-convert, XCD-MATCHED ----------
// Graph g is converted entirely by blocks with blockIdx%8 == g%8, i.e. on the
// SAME XCD whose L2 the gemm will read it from (gemm: XCD = bid&7 = g%8).
// z16 lines end up dirty-resident in the right L2 (16 graphs x 256 KB = 4 MB).
// Input z is read-once -> non-temporal loads (don't evict z16 being written).
__global__ __launch_bounds__(256)
void cvt_kernel(const float* __restrict__ z, _Float16* __restrict__ z16) {
  const int b = blockIdx.x;            // 8192 blocks
  const int x = b & 7;                 // XCD
  const int j = b >> 3;                // 0..1023
  const int g = x + 8 * (j >> 6);      // graph, g%8 == x
  const int chunk = j & 63;            // 8-row chunk within graph
  const size_t base = ((size_t)g * NODES + (size_t)chunk * 8) * DIM
                    + (size_t)threadIdx.x * 8;      // floats, 8 per thread
  const floatx4* p = reinterpret_cast<const floatx4*>(z + base);
  const floatx4 f0 = __builtin_nontemporal_load(p);
  const floatx4 f1 = __builtin_nontemporal_load(p + 1);
  *reinterpret_cast<half8*>(z16 + base) = pack8(f0, f1);  // normal store: keep in L2
}

// ---------- kernel 2: batched symmetric GEMM + sigmoid ----------
// 2048 blocks = 128 graphs x 16 tiles; 256 threads = 4 waves; each wave a
// 64x64 sub-tile via 4x4 mfma_f32_16x16x32_f16 accumulators.
// Staging: global_load_lds (16 B), XOR chunk swizzle c' = c ^ (row & 7).
// Epilogue: ZZ^T is symmetric -> block (tn,tm) stores output tile (tm,tn)
// TRANSPOSED, which puts the accumulator r-axis on the contiguous output axis:
// all stores become float4, and they are NON-TEMPORAL so the 134 MB output
// stream does not evict the 4 MB/XCD z16 working set from L2.
__global__ __launch_bounds__(256, 4)
void gemm_kernel(const _Float16* __restrict__ z16, float* __restrict__ out) {
  __shared__ __align__(16) _Float16 As[BM * BK];   // 16 KB, row = 8 chunks of 16 B
  __shared__ __align__(16) _Float16 Bs[BM * BK];

  const int bid = blockIdx.x;
  // XCD swizzle: all 16 tiles of a graph share bid%8 -> one XCD's L2 holds
  // only 16 graphs' z16 (4.0 MB ~ one L2), and matches cvt's placement.
  const int g    = (bid & 7) + 8 * (bid >> 7);
  const int tile = (bid >> 3) & 15;
  const int tn   = tile >> 2;
  const int tm   = tile & 3;

  const int tid  = threadIdx.x;
  const int lane = tid & 63;
  const int wave = tid >> 6;
  const int wRow = wave >> 1;
  const int wCol = wave & 1;
  const int lrow = lane & 15;
  const int quad = lane >> 4;

  const _Float16* zA = z16 + ((size_t)g * NODES + tn * BM) * DIM;
  const _Float16* zB = z16 + ((size_t)g * NODES + tm * BM) * DIM;

  // staging decomposition: 16 instructions/tile, inst q covers rows q*8..q*8+7
  // lane -> (local row = lane>>3, chunk c = lane&7), global chunk = c ^ (row&7)
  const int sRow = lane >> 3;                 // 0..7
  const int sCp  = (lane & 7) ^ sRow;         // swizzled global chunk index
  const size_t sOffH = (size_t)sRow * DIM + sCp * 8;  // halfs, + row-block*8*DIM

  floatx4 acc[4][4];
#pragma unroll
  for (int i = 0; i < 4; ++i)
#pragma unroll
    for (int j = 0; j < 4; ++j)
      acc[i][j] = (floatx4){0.f, 0.f, 0.f, 0.f};

  for (int kk = 0; kk < DIM; kk += BK) {
#pragma unroll
    for (int it = 0; it < 4; ++it) {
      const int q = wave * 4 + it;            // 0..15, rows q*8..q*8+7
      const _Float16* gA = zA + (size_t)q * 8 * DIM + kk + sOffH;
      const _Float16* gB = zB + (size_t)q * 8 * DIM + kk + sOffH;
      async_ld16(gA, &As[q * 512]);           // q*1024 B
      async_ld16(gB, &Bs[q * 512]);
    }
    __syncthreads();                          // drains vmcnt

#pragma unroll
    for (int ks = 0; ks < 2; ++ks) {
      half8 af[4], bf[4];
#pragma unroll
      for (int i = 0; i < 4; ++i) {
        const int row = wRow * 64 + i * 16 + lrow;
        const int cp = (ks * 4 + quad) ^ (lrow & 7);
        af[i] = *reinterpret_cast<const half8*>(&As[row * BK + cp * 8]);
      }
#pragma unroll
      for (int j = 0; j < 4; ++j) {
        const int row = wCol * 64 + j * 16 + lrow;
        const int cp = (ks * 4 + quad) ^ (lrow & 7);
        bf[j] = *reinterpret_cast<const half8*>(&Bs[row * BK + cp * 8]);
      }
#pragma unroll
      for (int i = 0; i < 4; ++i)
#pragma unroll
        for (int j = 0; j < 4; ++j)
          acc[i][j] = __builtin_amdgcn_mfma_f32_16x16x32_f16(af[i], bf[j], acc[i][j], 0, 0, 0);
    }
    __syncthreads();
  }

  // epilogue: sigmoid + transposed fp32 store (float4, non-temporal).
  // acc[i][j][r] = C[n, m] with n = tn*128 + wRow*64 + i*16 + quad*4 + r
  //                        m = tm*128 + wCol*64 + j*16 + lrow
  // We write out[m][n] = sigmoid(dot(z_m, z_n)) — exact same value, and the
  // grid contains every (tn,tm) pair, so each output element is written once.
  float* outg = out + (size_t)g * NODES * NODES;
  const int nBase = tn * BM + wRow * 64;      // output COLUMN base
  const int mBase = tm * BM + wCol * 64;      // output ROW    base
#pragma unroll
  for (int j = 0; j < 4; ++j) {
    const int m = mBase + j * 16 + lrow;
    float* rowp = outg + (size_t)m * NODES;
#pragma unroll
    for (int i = 0; i < 4; ++i) {
      const int n0 = nBase + i * 16 + quad * 4;
      floatx4 v;
#pragma unroll
      for (int r = 0; r < 4; ++r) {
        const float x = acc[i][j][r];
        v[r] = __builtin_amdgcn_rcpf(1.0f + __expf(-x));
      }
      __builtin_nontemporal_store(v, reinterpret_cast<floatx4*>(rowp + n0));
    }
  }
}

// ---------- fallback (round-3 kernel) if workspace is too small ----------
constexpr int LSTR = 72;
__global__ __launch_bounds__(256, 4)
void fallback_kernel(const float* __restrict__ z, float* __restrict__ out) {
  __shared__ _Float16 As[BM * LSTR];
  __shared__ _Float16 Bs[BM * LSTR];
  const int bid = blockIdx.x;
  const int g    = (bid & 7) + 8 * (bid >> 7);
  const int tile = (bid >> 3) & 15;
  const int tn   = tile >> 2;
  const int tm   = tile & 3;
  const int tid  = threadIdx.x;
  const int lane = tid & 63;
  const int wave = tid >> 6;
  const int wRow = wave >> 1;
  const int wCol = wave & 1;
  const int lrow = lane & 15;
  const int quad = lane >> 4;
  const float* zA = z + ((size_t)g * NODES + tn * BM) * DIM;
  const float* zB = z + ((size_t)g * NODES + tm * BM) * DIM;
  const int srow  = tid >> 1;
  const int shalf = tid & 1;
  floatx4 acc[4][4];
#pragma unroll
  for (int i = 0; i < 4; ++i)
#pragma unroll
    for (int j = 0; j < 4; ++j)
      acc[i][j] = (floatx4){0.f, 0.f, 0.f, 0.f};
  for (int kk = 0; kk < DIM; kk += BK) {
    {
      const float4* pa = reinterpret_cast<const float4*>(zA + srow * DIM + kk + shalf * 32);
      _Float16* da = &As[srow * LSTR + shalf * 32];
      float4 f0 = pa[0], f1 = pa[1], f2 = pa[2], f3 = pa[3];
      *reinterpret_cast<half8*>(da)     = pack8(f0, f1);
      *reinterpret_cast<half8*>(da + 8) = pack8(f2, f3);
      f0 = pa[4]; f1 = pa[5]; f2 = pa[6]; f3 = pa[7];
      *reinterpret_cast<half8*>(da + 16) = pack8(f0, f1);
      *reinterpret_cast<half8*>(da + 24) = pack8(f2, f3);
    }
    {
      const float4* pb = reinterpret_cast<const float4*>(zB + srow * DIM + kk + shalf * 32);
      _Float16* db = &Bs[srow * LSTR + shalf * 32];
      float4 f0 = pb[0], f1 = pb[1], f2 = pb[2], f3 = pb[3];
      *reinterpret_cast<half8*>(db)     = pack8(f0, f1);
      *reinterpret_cast<half8*>(db + 8) = pack8(f2, f3);
      f0 = pb[4]; f1 = pb[5]; f2 = pb[6]; f3 = pb[7];
      *reinterpret_cast<half8*>(db + 16) = pack8(f0, f1);
      *reinterpret_cast<half8*>(db + 24) = pack8(f2, f3);
    }
    __syncthreads();
#pragma unroll
    for (int ks = 0; ks < 2; ++ks) {
      half8 af[4], bf[4];
#pragma unroll
      for (int i = 0; i < 4; ++i)
        af[i] = *reinterpret_cast<const half8*>(
            &As[(wRow * 64 + i * 16 + lrow) * LSTR + ks * 32 + quad * 8]);
#pragma unroll
      for (int j = 0; j < 4; ++j)
        bf[j] = *reinterpret_cast<const half8*>(
            &Bs[(wCol * 64 + j * 16 + lrow) * LSTR + ks * 32 + quad * 8]);
#pragma unroll
      for (int i = 0; i < 4; ++i)
#pragma unroll
        for (int j = 0; j < 4; ++j)
          acc[i][j] = __builtin_amdgcn_mfma_f32_16x16x32_f16(af[i], bf[j], acc[i][j], 0, 0, 0);
    }
    __syncthreads();
  }
  // same transposed float4 non-temporal epilogue as the main kernel
  float* outg = out + (size_t)g * NODES * NODES;
  const int nBase = tn * BM + wRow * 64;
  const int mBase = tm * BM + wCol * 64;
#pragma unroll
  for (int j = 0; j < 4; ++j) {
    const int m = mBase + j * 16 + lrow;
    float* rowp = outg + (size_t)m * NODES;
#pragma unroll
    for (int i = 0; i < 4; ++i) {
      const int n0 = nBase + i * 16 + quad * 4;
      floatx4 v;
#pragma unroll
      for (int r = 0; r < 4; ++r) {
        const float x = acc[i][j][r];
        v[r] = __builtin_amdgcn_rcpf(1.0f + __expf(-x));
      }
      __builtin_nontemporal_store(v, reinterpret_cast<floatx4*>(rowp + n0));
    }
  }
}

} // namespace

extern "C" void kernel_launch(void* const* d_in, const int* in_sizes, int n_in,
                              void* d_out, int out_size, void* d_ws, size_t ws_size,
                              hipStream_t stream) {
  const float* z = (const float*)d_in[0];
  float* out = (float*)d_out;
  const size_t need = (size_t)128 * 512 * 256 * sizeof(_Float16);  // 33.6 MB
  if (ws_size >= need) {
    _Float16* z16 = (_Float16*)d_ws;
    hipLaunchKernelGGL(cvt_kernel, dim3(8192), dim3(256), 0, stream, z, z16);
    hipLaunchKernelGGL(gemm_kernel, dim3(128 * 16), dim3(256), 0, stream, z16, out);
  } else {
    hipLaunchKernelGGL(fallback_kernel, dim3(128 * 16), dim3(256), 0, stream, z, out);
  }
}

// Round 2
// 229.701 us; speedup vs baseline: 1.0109x; 1.0109x over previous
//
#include <hip/hip_runtime.h>

typedef __fp16 fp16x2 __attribute__((ext_vector_type(2)));   // cvt_pkrtz result type
typedef _Float16 half8 __attribute__((ext_vector_type(8)));
typedef float floatx4 __attribute__((ext_vector_type(4)));

namespace {

constexpr int NODES = 512;   // nodes per graph
constexpr int DIM   = 256;   // latent dim
constexpr int BM    = 128;   // block tile (rows and cols)
constexpr int BK    = 64;    // K-step per LDS stage (fp16): row = 128 B = 8 x 16B chunks

union Cvt8 { fp16x2 h2[4]; half8 h8; };

__device__ inline half8 pack8(const floatx4 f0, const floatx4 f1) {
  Cvt8 c;
  c.h2[0] = __builtin_amdgcn_cvt_pkrtz(f0.x, f0.y);
  c.h2[1] = __builtin_amdgcn_cvt_pkrtz(f0.z, f0.w);
  c.h2[2] = __builtin_amdgcn_cvt_pkrtz(f1.x, f1.y);
  c.h2[3] = __builtin_amdgcn_cvt_pkrtz(f1.z, f1.w);
  return c.h8;
}

__device__ inline half8 pack8(const float4 f0, const float4 f1) {
  Cvt8 c;
  c.h2[0] = __builtin_amdgcn_cvt_pkrtz(f0.x, f0.y);
  c.h2[1] = __builtin_amdgcn_cvt_pkrtz(f0.z, f0.w);
  c.h2[2] = __builtin_amdgcn_cvt_pkrtz(f1.x, f1.y);
  c.h2[3] = __builtin_amdgcn_cvt_pkrtz(f1.z, f1.w);
  return c.h8;
}

// async 16-B global -> LDS DMA; LDS dest = wave-uniform base + lane*16
__device__ inline void async_ld16(const void* g, void* lds) {
  __builtin_amdgcn_global_load_lds(
      (const __attribute__((address_space(1))) unsigned int*)g,
      (__attribute__((address_space(3))) unsigned int*)lds,
      16, 0, 0);
}

__device__ inline float sigmoidf(float x) {
  return __builtin_amdgcn_rcpf(1.0f + __expf(-x));
}

// ---------- kernel 1: fp32 -> fp16 pre-convert, XCD-MATCHED ----------
// Graph g is converted entirely by blocks with blockIdx%8 == g%8, i.e. on the
// SAME XCD whose L2 the gemm will read it from (gemm: XCD = bid&7 = g%8).
// Input z is read-once -> non-temporal loads; z16 store is NORMAL (keep in L2).
__global__ __launch_bounds__(256)
void cvt_kernel(const float* __restrict__ z, _Float16* __restrict__ z16) {
  const int b = blockIdx.x;            // 8192 blocks
  const int x = b & 7;                 // XCD
  const int j = b >> 3;                // 0..1023
  const int g = x + 8 * (j >> 6);      // graph, g%8 == x
  const int chunk = j & 63;            // 8-row chunk within graph
  const size_t base = ((size_t)g * NODES + (size_t)chunk * 8) * DIM
                    + (size_t)threadIdx.x * 8;      // floats, 8 per thread
  const floatx4* p = reinterpret_cast<const floatx4*>(z + base);
  const floatx4 f0 = __builtin_nontemporal_load(p);
  const floatx4 f1 = __builtin_nontemporal_load(p + 1);
  *reinterpret_cast<half8*>(z16 + base) = pack8(f0, f1);
}

// ---------- kernel 2: symmetric batched GEMM + sigmoid, 10 tiles/graph ----------
// C = Z Z^T is exactly symmetric (MFMA k-reduction order is independent of
// operand position), so only tiles tn<=tm are computed: 10 of 16 per graph.
//   grid = 128 graphs x 10 tiles = 1280 blocks, 256 threads = 4 waves,
//   each wave a 64x64 sub-tile via 4x4 mfma_f32_16x16x32_f16.
// Diagonal tiles (tn==tm) stage only ONE panel (A==B): reads 64 KB not 128 KB.
// Off-diagonal tiles write BOTH output blocks: (tm,tn) via float4 transposed
// stores, (tn,tm) via scalar stores (round-0-proven pattern). Normal stores
// everywhere -> L2 write-combines the 64-B segments into full lines.
__global__ __launch_bounds__(256, 4)
void gemm_kernel(const _Float16* __restrict__ z16, float* __restrict__ out) {
  __shared__ __align__(16) _Float16 As[BM * BK];   // 16 KB, row = 8 chunks of 16 B
  __shared__ __align__(16) _Float16 Bs[BM * BK];

  const int bid = blockIdx.x;
  // XCD swizzle: all 10 tiles of a graph share bid%8 -> one XCD's L2 holds
  // only 16 graphs' z16 (4.0 MB ~ one L2), matching cvt's placement.
  const int x    = bid & 7;
  const int j    = bid >> 3;           // 0..159
  const int ggrp = j / 10;             // 0..15
  const int t    = j - ggrp * 10;      // 0..9, unique tile id
  const int g    = x + 8 * ggrp;

  int tn, tm;
  if (t < 4)      { tn = 0; tm = t; }
  else if (t < 7) { tn = 1; tm = t - 3; }
  else if (t < 9) { tn = 2; tm = t - 5; }
  else            { tn = 3; tm = 3; }
  const bool diag = (tn == tm);

  const int tid  = threadIdx.x;
  const int lane = tid & 63;
  const int wave = tid >> 6;
  const int wRow = wave >> 1;
  const int wCol = wave & 1;
  const int lrow = lane & 15;
  const int quad = lane >> 4;

  const _Float16* zA = z16 + ((size_t)g * NODES + tn * BM) * DIM;
  const _Float16* zB = z16 + ((size_t)g * NODES + tm * BM) * DIM;

  // staging decomposition: 16 instructions/tile, inst q covers rows q*8..q*8+7
  // lane -> (local row = lane>>3, chunk c = lane&7), global chunk = c ^ (row&7)
  const int sRow = lane >> 3;                 // 0..7
  const int sCp  = (lane & 7) ^ sRow;         // swizzled global chunk index
  const size_t sOffH = (size_t)sRow * DIM + sCp * 8;  // halfs, + row-block*8*DIM

  // diagonal tiles read B-fragments from As (A==B, half the staging traffic)
  const _Float16* Bsrc = diag ? As : Bs;

  floatx4 acc[4][4];
#pragma unroll
  for (int i = 0; i < 4; ++i)
#pragma unroll
    for (int jj = 0; jj < 4; ++jj)
      acc[i][jj] = (floatx4){0.f, 0.f, 0.f, 0.f};

  for (int kk = 0; kk < DIM; kk += BK) {
#pragma unroll
    for (int it = 0; it < 4; ++it) {
      const int q = wave * 4 + it;            // 0..15, rows q*8..q*8+7
      const _Float16* gA = zA + (size_t)q * 8 * DIM + kk + sOffH;
      async_ld16(gA, &As[q * 512]);           // q*1024 B
      if (!diag) {
        const _Float16* gB = zB + (size_t)q * 8 * DIM + kk + sOffH;
        async_ld16(gB, &Bs[q * 512]);
      }
    }
    __syncthreads();                          // drains vmcnt

#pragma unroll
    for (int ks = 0; ks < 2; ++ks) {
      half8 af[4], bf[4];
#pragma unroll
      for (int i = 0; i < 4; ++i) {
        const int row = wRow * 64 + i * 16 + lrow;
        const int cp = (ks * 4 + quad) ^ (lrow & 7);
        af[i] = *reinterpret_cast<const half8*>(&As[row * BK + cp * 8]);
      }
#pragma unroll
      for (int jj = 0; jj < 4; ++jj) {
        const int row = wCol * 64 + jj * 16 + lrow;
        const int cp = (ks * 4 + quad) ^ (lrow & 7);
        bf[jj] = *reinterpret_cast<const half8*>(&Bsrc[row * BK + cp * 8]);
      }
#pragma unroll
      for (int i = 0; i < 4; ++i)
#pragma unroll
        for (int jj = 0; jj < 4; ++jj)
          acc[i][jj] = __builtin_amdgcn_mfma_f32_16x16x32_f16(af[i], bf[jj], acc[i][jj], 0, 0, 0);
    }
    __syncthreads();
  }

  // epilogue: sigmoid once, write block (tm,tn) transposed with float4;
  // off-diagonal also writes block (tn,tm) with scalar stores.
  // acc[i][j][r] = C[n, m], n = tn*128 + wRow*64 + i*16 + quad*4 + r
  //                         m = tm*128 + wCol*64 + j*16 + lrow
  float* outg = out + (size_t)g * NODES * NODES;
  const int nBase = tn * BM + wRow * 64;
  const int mBase = tm * BM + wCol * 64;
#pragma unroll
  for (int jj = 0; jj < 4; ++jj) {
    const int m = mBase + jj * 16 + lrow;
    float* rowp = outg + (size_t)m * NODES;
#pragma unroll
    for (int i = 0; i < 4; ++i) {
      const int n0 = nBase + i * 16 + quad * 4;
      floatx4 v;
#pragma unroll
      for (int r = 0; r < 4; ++r)
        v[r] = sigmoidf(acc[i][jj][r]);
      *reinterpret_cast<floatx4*>(rowp + n0) = v;          // out[m][n0..n0+3]
      if (!diag) {
#pragma unroll
        for (int r = 0; r < 4; ++r)
          outg[(size_t)(n0 + r) * NODES + m] = v[r];       // out[n][m]
      }
    }
  }
}

// ---------- fallback (round-3 kernel) if workspace is too small ----------
constexpr int LSTR = 72;
__global__ __launch_bounds__(256, 4)
void fallback_kernel(const float* __restrict__ z, float* __restrict__ out) {
  __shared__ _Float16 As[BM * LSTR];
  __shared__ _Float16 Bs[BM * LSTR];
  const int bid = blockIdx.x;
  const int g    = (bid & 7) + 8 * (bid >> 7);
  const int tile = (bid >> 3) & 15;
  const int tn   = tile >> 2;
  const int tm   = tile & 3;
  const int tid  = threadIdx.x;
  const int lane = tid & 63;
  const int wave = tid >> 6;
  const int wRow = wave >> 1;
  const int wCol = wave & 1;
  const int lrow = lane & 15;
  const int quad = lane >> 4;
  const float* zA = z + ((size_t)g * NODES + tn * BM) * DIM;
  const float* zB = z + ((size_t)g * NODES + tm * BM) * DIM;
  const int srow  = tid >> 1;
  const int shalf = tid & 1;
  floatx4 acc[4][4];
#pragma unroll
  for (int i = 0; i < 4; ++i)
#pragma unroll
    for (int j = 0; j < 4; ++j)
      acc[i][j] = (floatx4){0.f, 0.f, 0.f, 0.f};
  for (int kk = 0; kk < DIM; kk += BK) {
    {
      const float4* pa = reinterpret_cast<const float4*>(zA + srow * DIM + kk + shalf * 32);
      _Float16* da = &As[srow * LSTR + shalf * 32];
      float4 f0 = pa[0], f1 = pa[1], f2 = pa[2], f3 = pa[3];
      *reinterpret_cast<half8*>(da)     = pack8(f0, f1);
      *reinterpret_cast<half8*>(da + 8) = pack8(f2, f3);
      f0 = pa[4]; f1 = pa[5]; f2 = pa[6]; f3 = pa[7];
      *reinterpret_cast<half8*>(da + 16) = pack8(f0, f1);
      *reinterpret_cast<half8*>(da + 24) = pack8(f2, f3);
    }
    {
      const float4* pb = reinterpret_cast<const float4*>(zB + srow * DIM + kk + shalf * 32);
      _Float16* db = &Bs[srow * LSTR + shalf * 32];
      float4 f0 = pb[0], f1 = pb[1], f2 = pb[2], f3 = pb[3];
      *reinterpret_cast<half8*>(db)     = pack8(f0, f1);
      *reinterpret_cast<half8*>(db + 8) = pack8(f2, f3);
      f0 = pb[4]; f1 = pb[5]; f2 = pb[6]; f3 = pb[7];
      *reinterpret_cast<half8*>(db + 16) = pack8(f0, f1);
      *reinterpret_cast<half8*>(db + 24) = pack8(f2, f3);
    }
    __syncthreads();
#pragma unroll
    for (int ks = 0; ks < 2; ++ks) {
      half8 af[4], bf[4];
#pragma unroll
      for (int i = 0; i < 4; ++i)
        af[i] = *reinterpret_cast<const half8*>(
            &As[(wRow * 64 + i * 16 + lrow) * LSTR + ks * 32 + quad * 8]);
#pragma unroll
      for (int j = 0; j < 4; ++j)
        bf[j] = *reinterpret_cast<const half8*>(
            &Bs[(wCol * 64 + j * 16 + lrow) * LSTR + ks * 32 + quad * 8]);
#pragma unroll
      for (int i = 0; i < 4; ++i)
#pragma unroll
        for (int j = 0; j < 4; ++j)
          acc[i][j] = __builtin_amdgcn_mfma_f32_16x16x32_f16(af[i], bf[j], acc[i][j], 0, 0, 0);
    }
    __syncthreads();
  }
  float* outg = out + (size_t)g * NODES * NODES;
  const int nBase = tn * BM + wRow * 64;
  const int mBase = tm * BM + wCol * 64;
#pragma unroll
  for (int i = 0; i < 4; ++i) {
#pragma unroll
    for (int j = 0; j < 4; ++j) {
      const int m = mBase + j * 16 + lrow;
#pragma unroll
      for (int r = 0; r < 4; ++r) {
        const int n = nBase + i * 16 + quad * 4 + r;
        const float x = acc[i][j][r];
        outg[(size_t)n * NODES + m] = sigmoidf(x);
      }
    }
  }
}

} // namespace

extern "C" void kernel_launch(void* const* d_in, const int* in_sizes, int n_in,
                              void* d_out, int out_size, void* d_ws, size_t ws_size,
                              hipStream_t stream) {
  const float* z = (const float*)d_in[0];
  float* out = (float*)d_out;
  const size_t need = (size_t)128 * 512 * 256 * sizeof(_Float16);  // 33.6 MB
  if (ws_size >= need) {
    _Float16* z16 = (_Float16*)d_ws;
    hipLaunchKernelGGL(cvt_kernel, dim3(8192), dim3(256), 0, stream, z, z16);
    hipLaunchKernelGGL(gemm_kernel, dim3(128 * 10), dim3(256), 0, stream, z16, out);
  } else {
    hipLaunchKernelGGL(fallback_kernel, dim3(128 * 16), dim3(256), 0, stream, z, out);
  }
}

// Round 3
// 193.013 us; speedup vs baseline: 1.2030x; 1.1901x over previous
//
#include <hip/hip_runtime.h>

typedef __fp16 fp16x2 __attribute__((ext_vector_type(2)));   // cvt_pkrtz result type
typedef _Float16 half8 __attribute__((ext_vector_type(8)));
typedef float floatx4 __attribute__((ext_vector_type(4)));

namespace {

constexpr int NODES = 512;   // nodes per graph
constexpr int DIM   = 256;   // latent dim (floats)
constexpr int BM    = 128;   // block tile (rows and cols)
constexpr int BKF   = 64;    // K-step in floats: fp32 row = 256 B = 16 x 16-B chunks

union Cvt8 { fp16x2 h2[4]; half8 h8; };

__device__ inline half8 pack8(const floatx4 f0, const floatx4 f1) {
  Cvt8 c;
  c.h2[0] = __builtin_amdgcn_cvt_pkrtz(f0.x, f0.y);
  c.h2[1] = __builtin_amdgcn_cvt_pkrtz(f0.z, f0.w);
  c.h2[2] = __builtin_amdgcn_cvt_pkrtz(f1.x, f1.y);
  c.h2[3] = __builtin_amdgcn_cvt_pkrtz(f1.z, f1.w);
  return c.h8;
}

// async 16-B global -> LDS DMA; LDS dest = wave-uniform base + lane*16
__device__ inline void async_ld16(const void* g, void* lds) {
  __builtin_amdgcn_global_load_lds(
      (const __attribute__((address_space(1))) unsigned int*)g,
      (__attribute__((address_space(3))) unsigned int*)lds,
      16, 0, 0);
}

__device__ inline float sigmoidf(float x) {
  return __builtin_amdgcn_rcpf(1.0f + __expf(-x));
}

// ---------- fused kernel: fp32 stage -> fp16 fragments -> MFMA -> sigmoid ----
// ONE kernel, no fp16 intermediate in HBM. C = Z Z^T is exactly symmetric
// (same product set either side), so only tiles tn<=tm are computed:
//   grid = 128 graphs x 10 tiles = 1280 blocks, 256 threads = 4 waves,
//   each wave a 64x64 sub-tile via 4x4 mfma_f32_16x16x32_f16.
// Staging: global_load_lds of FP32 panels (32 KB/panel/K-step), LDS linear,
// source pre-swizzled chunk c_src = c ^ (row & 15); fragment reads use the
// same XOR -> uniform bank load (8/bank per ds_read_b128, conflict-free).
// fp32 -> fp16 conversion happens at fragment-build (cvt_pkrtz x4).
// Diagonal tiles (tn==tm) stage ONE panel (A==B): half the read traffic.
// Off-diagonal tiles write both output blocks: (tm,tn) via float4 rows,
// (tn,tm) via the scalar mirror. Normal stores -> L2 write-combining.
// fp32 panel re-reads across the 10 tiles of a graph dedup in the XCD-local
// L2: bid%8 keys both graph and XCD, ~3.2 MB resident/XCD < 4 MB L2.
__global__ __launch_bounds__(256, 2)
void fused_kernel(const float* __restrict__ z, float* __restrict__ out) {
  __shared__ __align__(16) float As[BM * BKF];   // 32 KB
  __shared__ __align__(16) float Bs[BM * BKF];   // 32 KB

  const int bid = blockIdx.x;
  const int x    = bid & 7;            // XCD
  const int j    = bid >> 3;           // 0..159
  const int ggrp = j / 10;             // 0..15
  const int t    = j - ggrp * 10;      // 0..9, unique tile id
  const int g    = x + 8 * ggrp;       // graph, g%8 == XCD

  int tn, tm;
  if (t < 4)      { tn = 0; tm = t; }
  else if (t < 7) { tn = 1; tm = t - 3; }
  else if (t < 9) { tn = 2; tm = t - 5; }
  else            { tn = 3; tm = 3; }
  const bool diag = (tn == tm);

  const int tid  = threadIdx.x;
  const int lane = tid & 63;
  const int wave = tid >> 6;
  const int wRow = wave >> 1;
  const int wCol = wave & 1;
  const int lrow = lane & 15;
  const int quad = lane >> 4;

  const float* zA = z + ((size_t)g * NODES + tn * BM) * DIM;
  const float* zB = z + ((size_t)g * NODES + tm * BM) * DIM;

  // staging decomposition: 32 insts per 32-KB panel per K-step, inst q covers
  // rows q*4..q*4+3 (4 rows x 256 B = 1 KB = 64 lanes x 16 B).
  // lane -> (local row = lane>>4, LDS chunk c = lane&15); source chunk is
  // pre-swizzled: c_src = c ^ (row & 15).
  const int sRowL = lane >> 4;          // 0..3
  const int sC    = lane & 15;          // LDS chunk this lane fills

  const float* Bsrc = diag ? As : Bs;   // diagonal: B-fragments from As

  floatx4 acc[4][4];
#pragma unroll
  for (int i = 0; i < 4; ++i)
#pragma unroll
    for (int jj = 0; jj < 4; ++jj)
      acc[i][jj] = (floatx4){0.f, 0.f, 0.f, 0.f};

  for (int kk = 0; kk < DIM; kk += BKF) {
#pragma unroll
    for (int it = 0; it < 8; ++it) {
      const int q   = wave * 8 + it;            // 0..31
      const int row = q * 4 + sRowL;            // 0..127
      const int cs  = sC ^ (row & 15);          // swizzled source chunk
      const size_t srcOff = (size_t)row * DIM + kk + cs * 4;   // floats
      async_ld16(zA + srcOff, &As[q * 256]);    // inst base: q * 1024 B
      if (!diag) async_ld16(zB + srcOff, &Bs[q * 256]);
    }
    __syncthreads();                            // drains vmcnt + lgkm

#pragma unroll
    for (int ks = 0; ks < 2; ++ks) {
      const int cg0 = ks * 8 + quad * 2;        // first 16-B chunk of the frag
      half8 af[4], bf[4];
#pragma unroll
      for (int i = 0; i < 4; ++i) {
        const int row = wRow * 64 + i * 16 + lrow;      // row & 15 == lrow
        const floatx4 a0 = *reinterpret_cast<const floatx4*>(
            &As[row * BKF + ((cg0)     ^ lrow) * 4]);
        const floatx4 a1 = *reinterpret_cast<const floatx4*>(
            &As[row * BKF + ((cg0 + 1) ^ lrow) * 4]);
        af[i] = pack8(a0, a1);
      }
#pragma unroll
      for (int jj = 0; jj < 4; ++jj) {
        const int row = wCol * 64 + jj * 16 + lrow;     // row & 15 == lrow
        const floatx4 b0 = *reinterpret_cast<const floatx4*>(
            &Bsrc[row * BKF + ((cg0)     ^ lrow) * 4]);
        const floatx4 b1 = *reinterpret_cast<const floatx4*>(
            &Bsrc[row * BKF + ((cg0 + 1) ^ lrow) * 4]);
        bf[jj] = pack8(b0, b1);
      }
#pragma unroll
      for (int i = 0; i < 4; ++i)
#pragma unroll
        for (int jj = 0; jj < 4; ++jj)
          acc[i][jj] = __builtin_amdgcn_mfma_f32_16x16x32_f16(af[i], bf[jj], acc[i][jj], 0, 0, 0);
    }
    __syncthreads();
  }

  // epilogue: sigmoid once; write block (tm,tn) transposed with float4 rows;
  // off-diagonal also writes the mirror block (tn,tm) with scalar stores.
  // acc[i][j][r] = C[n, m], n = tn*128 + wRow*64 + i*16 + quad*4 + r
  //                         m = tm*128 + wCol*64 + j*16 + lrow
  float* outg = out + (size_t)g * NODES * NODES;
  const int nBase = tn * BM + wRow * 64;
  const int mBase = tm * BM + wCol * 64;
#pragma unroll
  for (int jj = 0; jj < 4; ++jj) {
    const int m = mBase + jj * 16 + lrow;
    float* rowp = outg + (size_t)m * NODES;
#pragma unroll
    for (int i = 0; i < 4; ++i) {
      const int n0 = nBase + i * 16 + quad * 4;
      floatx4 v;
#pragma unroll
      for (int r = 0; r < 4; ++r)
        v[r] = sigmoidf(acc[i][jj][r]);
      *reinterpret_cast<floatx4*>(rowp + n0) = v;          // out[m][n0..n0+3]
      if (!diag) {
#pragma unroll
        for (int r = 0; r < 4; ++r)
          outg[(size_t)(n0 + r) * NODES + m] = v[r];       // out[n][m]
      }
    }
  }
}

} // namespace

extern "C" void kernel_launch(void* const* d_in, const int* in_sizes, int n_in,
                              void* d_out, int out_size, void* d_ws, size_t ws_size,
                              hipStream_t stream) {
  const float* z = (const float*)d_in[0];
  float* out = (float*)d_out;
  (void)d_ws; (void)ws_size;
  hipLaunchKernelGGL(fused_kernel, dim3(128 * 10), dim3(256), 0, stream, z, out);
}